// Round 6
// baseline (348.788 us; speedup 1.0000x reference)
//
#include <hip/hip_runtime.h>
#include <math.h>

#define BLK 256
#define SBLK 1024
#define HBINS 16384
#define BPT 16                      // bins per thread in select
#define CSH 42
#define QMASK ((1ULL << CSH) - 1ULL)

__device__ __forceinline__ float bce_logits(float x, float t){
    return fmaxf(x, 0.f) - x * t + log1pf(expf(-fabsf(x)));
}
__device__ __forceinline__ float smooth_l1(float x){
    float ax = fabsf(x);
    return ax < 1.f ? 0.5f * x * x : ax - 0.5f;
}

// All 3 scales, one dispatch, 4 anchors/thread, block GT y-cull (culled GTs
// have IoU==0 exactly -> semantics preserved). Negative BCE values go
// straight into a per-(s,b) global 16384-bin packed histogram:
//   bin = min(int(v*2048), 16383), payload = (1<<42) | int(v*2^22).
// count <= 64512 < 2^22; qsum <= 64512 * 6 * 2^22 < 2^42 -> fields never mix.
__global__ __launch_bounds__(BLK)
void det_map_all(const float* __restrict__ pred0,
                 const float* __restrict__ pred1,
                 const float* __restrict__ pred2,
                 const float* __restrict__ gtb,   // (B,32,4)
                 const int*   __restrict__ gtl,   // (B,32)
                 unsigned long long* __restrict__ hist,  // (3*B, HBINS)
                 int*   __restrict__ pos_cnt,     // 3*B
                 double* __restrict__ accum,
                 int B)
{
    const int b  = blockIdx.y;
    const int bx = blockIdx.x;

    const float* pred; int s, qloc, P, logW; float stride_f;
    if (bx < 48){      s=0; pred=pred0; P=16384; logW=7; stride_f= 8.f; qloc= bx      << 8; }
    else if (bx < 60){ s=1; pred=pred1; P= 4096; logW=6; stride_f=16.f; qloc=(bx-48) << 8; }
    else {             s=2; pred=pred2; P= 1024; logW=5; stride_f=32.f; qloc=(bx-60) << 8; }

    const int tid = threadIdx.x;
    const int lq  = 2*logW - 2;            // log2(P/4)
    const int Q4  = 1 << lq;
    const int a   = qloc >> lq;            // block-uniform (Q4 % 256 == 0)
    const int q   = qloc - a*Q4 + tid;
    const int pix0 = q << 2;

    const float half = 0.5f * (float)(3 + a) * stride_f;

    // block anchor y-extent for culling
    const int pixLo = (qloc - a*Q4) << 2;
    const int y0 = pixLo >> logW, y1 = (pixLo + BLK*4 - 1) >> logW;
    const float ymin = ((float)y0 + 0.5f) * stride_f - half;
    const float ymax = ((float)y1 + 0.5f) * stride_f + half;

    __shared__ float4 sg[32];
    __shared__ float  sarea[32];
    __shared__ int    sl[32];
    __shared__ int    s_cnt;

    {
        bool keep = false; float4 G;
        if (tid < 32){
            G = ((const float4*)gtb)[b * 32 + tid];
            keep = (G.y < ymax) && (G.w > ymin);
        }
        unsigned long long m = __ballot(keep);
        if (tid < 64){
            if (keep){
                int idx = (int)__popcll(m & ((1ULL << tid) - 1ULL));
                sg[idx] = G;
                sarea[idx] = (G.z - G.x) * (G.w - G.y);
                sl[idx] = gtl[b * 32 + tid];
            }
            if (tid == 0) s_cnt = (int)__popcll(m);
        }
    }
    __syncthreads();
    const int cnt = s_cnt;

    const int x0 = pix0 & ((1 << logW) - 1);
    const int y  = pix0 >> logW;
    const float cy = ((float)y + 0.5f) * stride_f;
    const float Ay = cy - half, Ay2 = cy + half;
    const float sz = 2.f * half;
    const float area_a = sz * sz;

    float ax[4], az[4];
    #pragma unroll
    for (int j = 0; j < 4; ++j){
        float cx = ((float)(x0 + j) + 0.5f) * stride_f;
        ax[j] = cx - half; az[j] = cx + half;
    }

    float bi[4] = {-1.f, -1.f, -1.f, -1.f};
    float bd[4] = { 1.f,  1.f,  1.f,  1.f};
    int   bg[4] = {0, 0, 0, 0};

    for (int g = 0; g < cnt; ++g){
        const float4 G = sg[g];
        const float sab = area_a + sarea[g];
        const float h = fmaxf(fminf(Ay2, G.w) - fmaxf(Ay, G.y), 0.f);
        #pragma unroll
        for (int j = 0; j < 4; ++j){
            float wdt = fmaxf(fminf(az[j], G.z) - fmaxf(ax[j], G.x), 0.f);
            float inter = wdt * h;
            float d = (sab - inter) + 1e-9f;
            if (inter * bd[j] > bi[j] * d){ bi[j] = inter; bd[j] = d; bg[j] = g; }
        }
    }

    const size_t cP = (size_t)P;
    const float* pp = pred + ((size_t)b * 24 + (size_t)a * 8) * cP + (size_t)pix0;
    const float4 p4v = *(const float4*)(pp + 4 * cP);
    const float p4a[4] = {p4v.x, p4v.y, p4v.z, p4v.w};

    unsigned long long* H = hist + (size_t)(s * B + b) * HBINS;

    float loss = 0.f; int pc = 0;
    #pragma unroll
    for (int j = 0; j < 4; ++j){
        const bool pos = 2.f * bi[j] >= bd[j];    // iou >= 0.5
        const bool neg = bi[j] < 0.4f * bd[j];    // iou <  0.4
        if (neg){
            float v = bce_logits(p4a[j], 0.f);
            int bin = min((int)(v * 2048.f), HBINS - 1);
            unsigned long long p = (1ULL << CSH) |
                (unsigned long long)(unsigned)(int)(v * 4194304.f);
            atomicAdd(&H[bin], p);
        }
        if (pos){
            pc++;
            const float4 G = sg[bg[j]];
            float axc = (ax[j] + az[j]) * 0.5f, ayc = (Ay + Ay2) * 0.5f;
            float aw = fmaxf(az[j] - ax[j], 1e-6f), ah = fmaxf(Ay2 - Ay, 1e-6f);
            float gxc = (G.x + G.z) * 0.5f, gyc = (G.y + G.w) * 0.5f;
            float gw = fmaxf(G.z - G.x, 1e-6f), gh = fmaxf(G.w - G.y, 1e-6f);
            float p0 = pp[0 * cP + j];
            float p1 = pp[1 * cP + j];
            float p2 = pp[2 * cP + j];
            float p3 = pp[3 * cP + j];
            loss += smooth_l1(p0 - (gxc - axc) / aw);
            loss += smooth_l1(p1 - (gyc - ayc) / ah);
            loss += smooth_l1(p2 - logf(gw / aw));
            loss += smooth_l1(p3 - logf(gh / ah));
            loss += bce_logits(p4a[j], 1.f);
            float c0 = pp[5 * cP + j];
            float c1 = pp[6 * cP + j];
            float c2 = pp[7 * cP + j];
            float m = fmaxf(c0, fmaxf(c1, c2));
            float lse = m + logf(expf(c0 - m) + expf(c1 - m) + expf(c2 - m));
            int tg = sl[bg[j]];
            float ct = (tg == 0) ? c0 : ((tg == 1) ? c1 : c2);
            loss += lse - ct;
        }
    }

    for (int off = 32; off > 0; off >>= 1){
        loss += __shfl_down(loss, off);
        pc   += __shfl_down(pc, off);
    }
    __shared__ float wsum[BLK / 64];
    __shared__ int   wcnt[BLK / 64];
    if ((tid & 63) == 0){ wsum[tid >> 6] = loss; wcnt[tid >> 6] = pc; }
    __syncthreads();
    if (tid == 0){
        float S = 0.f; int C = 0;
        for (int i = 0; i < BLK / 64; ++i){ S += wsum[i]; C += wcnt[i]; }
        if (S != 0.f) atomicAdd(accum, (double)S);
        if (C) atomicAdd(&pos_cnt[s * B + b], C);
    }
}

// One block per (scale,image): descending prefix over the 16384-bin packed
// histogram, closed-form top-K sum, ticket finalize.
// thresh = boundary bin lower bound; error <= rem * 2^-11 (<< tolerance).
__global__ __launch_bounds__(SBLK)
void det_select_hist(const unsigned long long* __restrict__ hist,
                     const int* __restrict__ pos_cnt,
                     double* __restrict__ accum,
                     unsigned* __restrict__ done_cnt,
                     float* __restrict__ out, int B)
{
    const int sb = blockIdx.x;
    const unsigned long long* H = hist + (size_t)sb * HBINS;
    const int tid = threadIdx.x, lane = tid & 63, w = tid >> 6;

    const int K = 3 * max(1, pos_cnt[sb]);

    // thread owns BPT consecutive bins; thread order == descending bin order
    const int start = HBINS - BPT * (tid + 1);
    unsigned long long chunk[BPT];
    unsigned long long tot = 0ULL;
    #pragma unroll
    for (int i = 0; i < BPT; ++i){ chunk[i] = H[start + i]; tot += chunk[i]; }

    const unsigned long long chunkP = tot;
    unsigned long long ci = tot;                     // inclusive prefix
    #pragma unroll
    for (int off = 1; off < 64; off <<= 1){
        unsigned long long cu = __shfl_up(ci, off);
        if (lane >= off) ci += cu;
    }
    __shared__ unsigned long long waveT[16];
    __shared__ unsigned long long waveOff[17];
    __shared__ double sh_sel;
    __shared__ int sh_done;
    if (lane == 63) waveT[w] = ci;
    if (tid == 0) sh_done = 0;
    __syncthreads();
    if (tid == 0){
        unsigned long long acc = 0ULL;
        #pragma unroll
        for (int i = 0; i < 16; ++i){ waveOff[i] = acc; acc += waveT[i]; }
        waveOff[16] = acc;
        if (K >= (int)(acc >> CSH)){                 // keep all negatives
            sh_done = 1;
            sh_sel = (double)(acc & QMASK) * (1.0 / 4194304.0);
        }
    }
    __syncthreads();

    if (!sh_done){
        const unsigned long long giP = waveOff[w] + ci;
        const unsigned long long geP = giP - chunkP;
        const int gi = (int)(giP >> CSH);
        const int ge = (int)(geP >> CSH);
        if (ge < K && K <= gi){
            int aboveC = ge;
            unsigned long long aboveQ = geP & QMASK;
            int bin = start; int rem = 0;
            #pragma unroll
            for (int i = BPT - 1; i >= 0; --i){
                int c = (int)(chunk[i] >> CSH);
                if (aboveC + c >= K){ bin = start + i; rem = K - aboveC; break; }
                aboveC += c;
                aboveQ += chunk[i] & QMASK;
            }
            float thresh = (float)bin * (1.f / 2048.f);
            sh_sel = (double)aboveQ * (1.0 / 4194304.0)
                   + (double)rem * (double)thresh;
        }
        __syncthreads();
    }

    if (tid == 0){
        atomicAdd(accum, sh_sel);
        __threadfence();
        unsigned t = atomicAdd(done_cnt, 1u);
        if (t == (unsigned)gridDim.x - 1u){
            __threadfence();
            double totd = atomicAdd(accum, 0.0);
            out[0] = (float)(totd / (double)B);
        }
    }
}

extern "C" void kernel_launch(void* const* d_in, const int* in_sizes, int n_in,
                              void* d_out, int out_size, void* d_ws, size_t ws_size,
                              hipStream_t stream)
{
    const float* gtb = (const float*)d_in[6];
    const int*   gtl = (const int*)d_in[7];
    const int B = in_sizes[6] / (32 * 4);   // 64

    double*   accum = (double*)d_ws;                               // @0
    unsigned* done  = (unsigned*)((char*)d_ws + 8);                // @8
    int*      pcnt  = (int*)((char*)d_ws + 16);                    // 3*B ints
    unsigned long long* hist = (unsigned long long*)((char*)d_ws + 1024);

    // zero accum/done/pcnt + 3*B*HBINS*8 histogram (~25 MB, ~5 us)
    hipMemsetAsync(d_ws, 0, 1024 + (size_t)(3 * B) * HBINS * 8, stream);

    det_map_all<<<dim3(63, B), BLK, 0, stream>>>(
        (const float*)d_in[0], (const float*)d_in[2], (const float*)d_in[4],
        gtb, gtl, hist, pcnt, accum, B);
    det_select_hist<<<dim3(3 * B), SBLK, 0, stream>>>(
        hist, pcnt, accum, done, (float*)d_out, B);
}

// Round 7
// 208.864 us; speedup vs baseline: 1.6699x; 1.6699x over previous
//
#include <hip/hip_runtime.h>
#include <math.h>

#define BLK 256
#define SBLK 1024
#define NBINS 2048
#define CSH 42
#define QMASK ((1ULL << CSH) - 1ULL)

__device__ __forceinline__ float bce_logits(float x, float t){
    return fmaxf(x, 0.f) - x * t + log1pf(expf(-fabsf(x)));
}
__device__ __forceinline__ float smooth_l1(float x){
    float ax = fabsf(x);
    return ax < 1.f ? 0.5f * x * x : ax - 0.5f;
}

// All 3 scales, one dispatch, 4 anchors/thread, block GT y-cull (culled GTs
// have IoU==0 exactly -> first-argmax/pos/neg semantics preserved).
// Per-block results go to plain-store slots (no zero-init, no atomics).
__global__ __launch_bounds__(BLK)
void det_map_all(const float* __restrict__ pred0,
                 const float* __restrict__ pred1,
                 const float* __restrict__ pred2,
                 const float* __restrict__ gtb,   // (B,32,4)
                 const int*   __restrict__ gtl,   // (B,32)
                 float* __restrict__ vals,        // (B,64512) neg BCE or -1
                 float* __restrict__ loss_slot,   // 63*B per-block map loss
                 int*   __restrict__ pcnt_slot,   // 63*B per-block pos count
                 unsigned* __restrict__ done_cnt, // zeroed by block (0,0)
                 int B)
{
    const int b  = blockIdx.y;
    const int bx = blockIdx.x;

    const float* pred; int s, qloc, P, logW; float stride_f; size_t vbase;
    if (bx < 48){      s=0; pred=pred0; P=16384; logW=7; stride_f= 8.f; qloc= bx      << 8; vbase=(size_t)b*49152; }
    else if (bx < 60){ s=1; pred=pred1; P= 4096; logW=6; stride_f=16.f; qloc=(bx-48) << 8; vbase=(size_t)B*49152 + (size_t)b*12288; }
    else {             s=2; pred=pred2; P= 1024; logW=5; stride_f=32.f; qloc=(bx-60) << 8; vbase=(size_t)B*49152 + (size_t)B*12288 + (size_t)b*3072; }

    const int tid = threadIdx.x;
    const int lq  = 2*logW - 2;            // log2(P/4)
    const int Q4  = 1 << lq;
    const int a   = qloc >> lq;            // block-uniform (Q4 % 256 == 0)
    const int q   = qloc - a*Q4 + tid;
    const int pix0 = q << 2;

    const float half = 0.5f * (float)(3 + a) * stride_f;

    // block anchor y-extent for culling
    const int pixLo = (qloc - a*Q4) << 2;
    const int y0 = pixLo >> logW, y1 = (pixLo + BLK*4 - 1) >> logW;
    const float ymin = ((float)y0 + 0.5f) * stride_f - half;
    const float ymax = ((float)y1 + 0.5f) * stride_f + half;

    __shared__ float4 sg[32];
    __shared__ float  sarea[32];
    __shared__ int    sl[32];
    __shared__ int    s_cnt;

    {
        bool keep = false; float4 G;
        if (tid < 32){
            G = ((const float4*)gtb)[b * 32 + tid];
            keep = (G.y < ymax) && (G.w > ymin);
        }
        unsigned long long m = __ballot(keep);
        if (tid < 64){
            if (keep){
                int idx = (int)__popcll(m & ((1ULL << tid) - 1ULL));
                sg[idx] = G;
                sarea[idx] = (G.z - G.x) * (G.w - G.y);
                sl[idx] = gtl[b * 32 + tid];
            }
            if (tid == 0) s_cnt = (int)__popcll(m);
        }
    }
    __syncthreads();
    const int cnt = s_cnt;

    const int x0 = pix0 & ((1 << logW) - 1);
    const int y  = pix0 >> logW;
    const float cy = ((float)y + 0.5f) * stride_f;
    const float Ay = cy - half, Ay2 = cy + half;
    const float sz = 2.f * half;
    const float area_a = sz * sz;

    float ax[4], az[4];
    #pragma unroll
    for (int j = 0; j < 4; ++j){
        float cx = ((float)(x0 + j) + 0.5f) * stride_f;
        ax[j] = cx - half; az[j] = cx + half;
    }

    float bi[4] = {-1.f, -1.f, -1.f, -1.f};
    float bd[4] = { 1.f,  1.f,  1.f,  1.f};
    int   bg[4] = {0, 0, 0, 0};

    for (int g = 0; g < cnt; ++g){
        const float4 G = sg[g];
        const float sab = area_a + sarea[g];
        const float h = fmaxf(fminf(Ay2, G.w) - fmaxf(Ay, G.y), 0.f);
        #pragma unroll
        for (int j = 0; j < 4; ++j){
            float wdt = fmaxf(fminf(az[j], G.z) - fmaxf(ax[j], G.x), 0.f);
            float inter = wdt * h;
            float d = (sab - inter) + 1e-9f;
            if (inter * bd[j] > bi[j] * d){ bi[j] = inter; bd[j] = d; bg[j] = g; }
        }
    }

    const size_t cP = (size_t)P;
    const float* pp = pred + ((size_t)b * 24 + (size_t)a * 8) * cP + (size_t)pix0;
    const float4 p4v = *(const float4*)(pp + 4 * cP);
    const float p4a[4] = {p4v.x, p4v.y, p4v.z, p4v.w};

    float vout[4];
    float loss = 0.f; int pc = 0;
    #pragma unroll
    for (int j = 0; j < 4; ++j){
        const bool pos = 2.f * bi[j] >= bd[j];    // iou >= 0.5
        const bool neg = bi[j] < 0.4f * bd[j];    // iou <  0.4
        vout[j] = neg ? bce_logits(p4a[j], 0.f) : -1.f;
        if (pos){
            pc++;
            const float4 G = sg[bg[j]];
            float axc = (ax[j] + az[j]) * 0.5f, ayc = (Ay + Ay2) * 0.5f;
            float aw = fmaxf(az[j] - ax[j], 1e-6f), ah = fmaxf(Ay2 - Ay, 1e-6f);
            float gxc = (G.x + G.z) * 0.5f, gyc = (G.y + G.w) * 0.5f;
            float gw = fmaxf(G.z - G.x, 1e-6f), gh = fmaxf(G.w - G.y, 1e-6f);
            float p0 = pp[0 * cP + j];
            float p1 = pp[1 * cP + j];
            float p2 = pp[2 * cP + j];
            float p3 = pp[3 * cP + j];
            loss += smooth_l1(p0 - (gxc - axc) / aw);
            loss += smooth_l1(p1 - (gyc - ayc) / ah);
            loss += smooth_l1(p2 - logf(gw / aw));
            loss += smooth_l1(p3 - logf(gh / ah));
            loss += bce_logits(p4a[j], 1.f);
            float c0 = pp[5 * cP + j];
            float c1 = pp[6 * cP + j];
            float c2 = pp[7 * cP + j];
            float m = fmaxf(c0, fmaxf(c1, c2));
            float lse = m + logf(expf(c0 - m) + expf(c1 - m) + expf(c2 - m));
            int tg = sl[bg[j]];
            float ct = (tg == 0) ? c0 : ((tg == 1) ? c1 : c2);
            loss += lse - ct;
        }
    }
    float4 vo = {vout[0], vout[1], vout[2], vout[3]};
    *(float4*)(vals + vbase + ((size_t)(qloc - a*Q4 + tid + a*Q4)) * 4) = vo;  // = qloc+tid

    for (int off = 32; off > 0; off >>= 1){
        loss += __shfl_down(loss, off);
        pc   += __shfl_down(pc, off);
    }
    __shared__ float wsum[BLK / 64];
    __shared__ int   wcnt[BLK / 64];
    if ((tid & 63) == 0){ wsum[tid >> 6] = loss; wcnt[tid >> 6] = pc; }
    __syncthreads();
    if (tid == 0){
        float S = 0.f; int C = 0;
        for (int i = 0; i < BLK / 64; ++i){ S += wsum[i]; C += wcnt[i]; }
        loss_slot[b * 63 + bx] = S;
        pcnt_slot[b * 63 + bx] = C;
        if (b == 0 && bx == 0) *done_cnt = 0u;   // visible to select via stream order
    }
}

// One 1024-thread block per (scale,image): sum map slots, 2-round packed-
// histogram top-K-sum over vals, slice total to slot, last-ticket reduce.
__global__ __launch_bounds__(SBLK)
void det_select(const float* __restrict__ vals,
                const float* __restrict__ loss_slot,
                const int* __restrict__ pcnt_slot,
                double* __restrict__ slice_tot,   // 3*B
                unsigned* __restrict__ done_cnt,
                float* __restrict__ out, int B)
{
    const int sb = blockIdx.x;
    const int s = sb / B, b = sb - s * B;
    const int N = (s == 0) ? 49152 : (s == 1) ? 12288 : 3072;
    size_t base = 0;
    if (s >= 1) base += (size_t)B * 49152;
    if (s >= 2) base += (size_t)B * 12288;
    const float* V = vals + base + (size_t)b * (size_t)N;

    const int tid = threadIdx.x;
    const int lane = tid & 63, w = tid >> 6;
    const int rep = w & 1;

    __shared__ unsigned long long h[2][NBINS];
    __shared__ unsigned long long waveT[16];
    __shared__ unsigned long long waveOff[17];
    __shared__ unsigned long long sh_aboveQ;
    __shared__ double sh_sel;
    __shared__ float sh_ml;
    __shared__ int sh_b1, sh_rem, sh_done, sh_K, sh_last;

    // ---- sum this slice's per-block map loss / pos count (wave 0) ----
    {
        const int nb   = (s == 0) ? 48 : (s == 1) ? 12 : 3;
        const int off0 = b * 63 + ((s == 0) ? 0 : (s == 1) ? 48 : 60);
        float ml = 0.f; int C = 0;
        if (tid < nb){ ml = loss_slot[off0 + tid]; C = pcnt_slot[off0 + tid]; }
        if (tid < 64){
            for (int off = 32; off > 0; off >>= 1){
                ml += __shfl_down(ml, off);
                C  += __shfl_down(C, off);
            }
            if (tid == 0){
                sh_ml = ml; sh_K = 3 * max(1, C);
                sh_rem = sh_K; sh_done = 0;
            }
        }
    }

    for (int round = 0; round < 2; ++round){
        for (int i = tid; i < NBINS; i += SBLK){ h[0][i] = 0ULL; h[1][i] = 0ULL; }
        __syncthreads();
        const int b1 = sh_b1;

        if (round == 0 || !sh_done){
            for (int i = tid * 4; i < N; i += SBLK * 4){
                float4 v4 = *(const float4*)(V + i);
                #pragma unroll
                for (int j = 0; j < 4; ++j){
                    float v = (j == 0) ? v4.x : (j == 1) ? v4.y : (j == 2) ? v4.z : v4.w;
                    if (!(v >= 0.f)) continue;
                    float t = v * 256.f;                 // exact (pow2)
                    int bin0 = min((int)t, NBINS - 1);
                    int key;
                    if (round == 0) key = bin0;
                    else {
                        if (bin0 != b1) continue;
                        float frac = t - (float)bin0;    // exact
                        key = min((int)(frac * 2048.f), NBINS - 1);
                    }
                    unsigned long long p = (1ULL << CSH) |
                        (unsigned long long)(unsigned)(int)(v * 4194304.f);
                    atomicAdd(&h[rep][key], p);
                }
            }
        }
        __syncthreads();
        if (sh_done) break;

        const int bhi = NBINS - 1 - 2 * tid;
        const unsigned long long c0p = h[0][bhi] + h[1][bhi];
        const unsigned long long c1p = h[0][bhi - 1] + h[1][bhi - 1];
        const unsigned long long pair = c0p + c1p;
        unsigned long long ci = pair;
        #pragma unroll
        for (int off = 1; off < 64; off <<= 1){
            unsigned long long cu = __shfl_up(ci, off);
            if (lane >= off) ci += cu;
        }
        if (lane == 63) waveT[w] = ci;
        __syncthreads();
        if (tid == 0){
            unsigned long long acc = 0ULL;
            #pragma unroll
            for (int i = 0; i < 16; ++i){ waveOff[i] = acc; acc += waveT[i]; }
            waveOff[16] = acc;
            if (round == 0 && sh_K >= (int)(acc >> CSH)){   // keep all negatives
                sh_done = 1;
                sh_sel = (double)(acc & QMASK) * (1.0 / 4194304.0);
            }
        }
        __syncthreads();
        if (sh_done) break;

        const int rem = sh_rem;
        const unsigned long long giP = waveOff[w] + ci;
        const unsigned long long geP = giP - pair;
        const int gi = (int)(giP >> CSH);
        const int ge = (int)(geP >> CSH);
        if (ge < rem && rem <= gi){
            const int c0 = (int)(c0p >> CSH);
            int bin, aboveC; unsigned long long aboveQ;
            if (ge + c0 >= rem){ bin = bhi;     aboveC = ge;      aboveQ = geP & QMASK; }
            else               { bin = bhi - 1; aboveC = ge + c0; aboveQ = (geP + c0p) & QMASK; }
            const int newRem = rem - aboveC;
            if (round == 0){
                sh_b1 = bin; sh_rem = newRem; sh_aboveQ = aboveQ;
            } else {
                float thresh = (float)sh_b1 * (1.f / 256.f) + (float)bin * (1.f / 524288.f);
                sh_sel = (double)(sh_aboveQ + aboveQ) * (1.0 / 4194304.0)
                       + (double)newRem * (double)thresh;
            }
        }
        __syncthreads();
    }

    // ---- slice total -> slot; last ticket block reduces all slices ----
    if (tid == 0){
        slice_tot[sb] = (double)sh_ml + sh_sel;
        __threadfence();
        unsigned t = atomicAdd(done_cnt, 1u);
        sh_last = (t == (unsigned)(gridDim.x - 1));
        if (sh_last) __threadfence();
    }
    __syncthreads();
    if (sh_last){
        double p = (tid < 3 * B) ? slice_tot[tid] : 0.0;
        for (int off = 32; off > 0; off >>= 1) p += __shfl_down(p, off);
        __shared__ double wred[16];
        if (lane == 0) wred[w] = p;
        __syncthreads();
        if (tid == 0){
            double tot = 0.0;
            for (int i = 0; i < 16; ++i) tot += wred[i];
            out[0] = (float)(tot / (double)B);
        }
    }
}

extern "C" void kernel_launch(void* const* d_in, const int* in_sizes, int n_in,
                              void* d_out, int out_size, void* d_ws, size_t ws_size,
                              hipStream_t stream)
{
    const float* gtb = (const float*)d_in[6];
    const int*   gtl = (const int*)d_in[7];
    const int B = in_sizes[6] / (32 * 4);   // 64

    unsigned* done      = (unsigned*)d_ws;                         // @0
    double*   slice_tot = (double*)((char*)d_ws + 64);             // 192 doubles
    float*    loss_slot = (float*)((char*)d_ws + 2048);            // 63*B floats
    int*      pcnt_slot = (int*)((char*)d_ws + 2048 + 16384);      // 63*B ints
    float*    vals      = (float*)((char*)d_ws + 36864);           // B*64512 floats

    det_map_all<<<dim3(63, B), BLK, 0, stream>>>(
        (const float*)d_in[0], (const float*)d_in[2], (const float*)d_in[4],
        gtb, gtl, vals, loss_slot, pcnt_slot, done, B);
    det_select<<<dim3(3 * B), SBLK, 0, stream>>>(
        vals, loss_slot, pcnt_slot, slice_tot, done, (float*)d_out, B);
}